// Round 1
// baseline (609.838 us; speedup 1.0000x reference)
//
#include <hip/hip_runtime.h>

#define ND 56
#define HD 64
#define ATOMS_PER_BLOCK 4

__global__ __launch_bounds__(256) void zero_kernel(float* __restrict__ p, int n) {
    int i = blockIdx.x * 256 + threadIdx.x;
    if (i < n) p[i] = 0.f;
}

// One wave (64 lanes) per atom; lane index = hidden unit.
// Computes per-atom energy (atomicAdd into per-config totals) and
// dEdD = d(total energy)/d(x) rows, written to workspace.
__global__ __launch_bounds__(256) void mlp_fwdbwd_kernel(
    const float* __restrict__ x,        // [natoms*ND]
    const int*   __restrict__ indices,  // [natoms]
    const float* __restrict__ W1,       // [ND*HD]
    const float* __restrict__ b1,       // [HD]
    const float* __restrict__ W2,       // [HD*HD]
    const float* __restrict__ b2,       // [HD]
    const float* __restrict__ W3,       // [HD]
    const float* __restrict__ b3,       // [1]
    float* __restrict__ out_e,          // [nconf]
    float* __restrict__ dEdD,           // [natoms*ND]
    int natoms)
{
    // pitch-65 padding: forward reads Ws[k*65+lane] and backward reads
    // Ws[lane*65+k] are both bank-conflict-free ((lane+k)%32 distinct).
    __shared__ float W1s[ND * 65];
    __shared__ float W2s[HD * 65];
    __shared__ float b1s[HD], b2s[HD], W3s[HD];
    __shared__ float xs[ATOMS_PER_BLOCK][ND];
    __shared__ float h1s[ATOMS_PER_BLOCK][HD];
    __shared__ float g2s[ATOMS_PER_BLOCK][HD];
    __shared__ float g1s[ATOMS_PER_BLOCK][HD];

    const int tid = threadIdx.x;

    for (int i = tid; i < ND * HD; i += 256) {
        int d = i / HD, h = i % HD;
        W1s[d * 65 + h] = W1[i];
    }
    for (int i = tid; i < HD * HD; i += 256) {
        int k = i / HD, h = i % HD;
        W2s[k * 65 + h] = W2[i];
    }
    if (tid < HD) {
        b1s[tid] = b1[tid];
        b2s[tid] = b2[tid];
        W3s[tid] = W3[tid];
    }

    const int w    = tid >> 6;    // wave id within block, 0..3
    const int lane = tid & 63;
    const int atom = blockIdx.x * ATOMS_PER_BLOCK + w;
    const bool valid = (atom < natoms);
    const float b3v = b3[0];

    if (valid && lane < ND) xs[w][lane] = x[(size_t)atom * ND + lane];
    __syncthreads();

    // ---- forward: layer 1 ----
    float z1 = b1s[lane];
    #pragma unroll 8
    for (int d = 0; d < ND; ++d) z1 += xs[w][d] * W1s[d * 65 + lane];
    float s1 = 1.f / (1.f + __expf(-z1));
    float h1v = z1 * s1;
    h1s[w][lane] = h1v;
    __syncthreads();

    // ---- forward: layer 2 ----
    float z2 = b2s[lane];
    #pragma unroll 8
    for (int k = 0; k < HD; ++k) z2 += h1s[w][k] * W2s[k * 65 + lane];
    float s2 = 1.f / (1.f + __expf(-z2));
    float h2v = z2 * s2;

    // ---- energy: e = sum_h h2[h]*W3[h] + b3 ----
    float ev = h2v * W3s[lane];
    #pragma unroll
    for (int off = 32; off > 0; off >>= 1) ev += __shfl_xor(ev, off);
    if (valid && lane == 0) atomicAdd(&out_e[indices[atom]], ev + b3v);

    // ---- backward ----
    // dz2[h] = W3[h] * silu'(z2[h]),   silu'(z) = s*(1 + z*(1-s))
    float g2 = W3s[lane] * (s2 * (1.f + z2 * (1.f - s2)));
    g2s[w][lane] = g2;
    __syncthreads();

    // dh1[k] = sum_h dz2[h]*W2[k,h];  dz1[k] = dh1[k]*silu'(z1[k])
    float t = 0.f;
    #pragma unroll 8
    for (int h = 0; h < HD; ++h) t += g2s[w][h] * W2s[lane * 65 + h];
    float g1 = t * (s1 * (1.f + z1 * (1.f - s1)));
    g1s[w][lane] = g1;
    __syncthreads();

    // dx[d] = sum_k dz1[k]*W1[d,k]
    if (lane < ND) {
        float acc = 0.f;
        #pragma unroll 8
        for (int k = 0; k < HD; ++k) acc += g1s[w][k] * W1s[lane * 65 + k];
        if (valid) dEdD[(size_t)atom * ND + lane] = acc;
    }
}

// 16 lanes per derivative row: lanes 0..13 each dot one float4 of the
// 56-float row; 16-lane shuffle reduce; lane 0 scatters with atomicAdd.
__global__ __launch_bounds__(256) void force_kernel(
    const float* __restrict__ xd,       // [M*ND]
    const int*   __restrict__ xd_indx,  // [M*3]
    const int*   __restrict__ unique_j, // [M]
    const float* __restrict__ dEdD,     // [natoms*ND]
    float* __restrict__ out_f,          // [3*natoms]
    int M)
{
    const long t = (long)blockIdx.x * 256 + threadIdx.x;
    const int  m   = (int)(t >> 4);
    const int  sub = (int)(t & 15);

    float partial = 0.f;
    if (m < M) {
        const int a = xd_indx[3 * m];  // col0: atom whose dEdD row we gather
        if (sub < 14) {
            const float4 u = reinterpret_cast<const float4*>(xd + (size_t)m * ND)[sub];
            const float4 v = reinterpret_cast<const float4*>(dEdD + (size_t)a * ND)[sub];
            partial = u.x * v.x + u.y * v.y + u.z * v.z + u.w * v.w;
        }
    }
    partial += __shfl_xor(partial, 1);
    partial += __shfl_xor(partial, 2);
    partial += __shfl_xor(partial, 4);
    partial += __shfl_xor(partial, 8);

    if (m < M && sub == 0) {
        const int coord = xd_indx[3 * m + 2];
        const int j     = unique_j[m];
        atomicAdd(&out_f[(size_t)j * 3 + coord], partial);
    }
}

extern "C" void kernel_launch(void* const* d_in, const int* in_sizes, int n_in,
                              void* d_out, int out_size, void* d_ws, size_t ws_size,
                              hipStream_t stream) {
    const float* x        = (const float*)d_in[0];
    const float* xd       = (const float*)d_in[1];
    const int*   indices  = (const int*)d_in[2];
    // d_in[3]: atoms_per_structure (only its length = nconf is needed)
    const int*   xd_indx  = (const int*)d_in[4];
    const int*   unique_j = (const int*)d_in[5];
    const float* W1 = (const float*)d_in[6];
    const float* b1 = (const float*)d_in[7];
    const float* W2 = (const float*)d_in[8];
    const float* b2 = (const float*)d_in[9];
    const float* W3 = (const float*)d_in[10];
    const float* b3 = (const float*)d_in[11];

    const int natoms = in_sizes[0] / ND;
    const int M      = in_sizes[1] / ND;
    const int nconf  = in_sizes[3];

    float* out_e = (float*)d_out;          // [nconf]
    float* out_f = out_e + nconf;          // [3*natoms]
    float* dEdD  = (float*)d_ws;           // [natoms*ND] floats (11.2 MB)

    // d_out is poisoned once and never re-zeroed between replays: zero it here.
    zero_kernel<<<(out_size + 255) / 256, 256, 0, stream>>>((float*)d_out, out_size);

    mlp_fwdbwd_kernel<<<(natoms + ATOMS_PER_BLOCK - 1) / ATOMS_PER_BLOCK, 256, 0, stream>>>(
        x, indices, W1, b1, W2, b2, W3, b3, out_e, dEdD, natoms);

    const long fthreads = (long)M * 16;
    force_kernel<<<(unsigned)((fthreads + 255) / 256), 256, 0, stream>>>(
        xd, xd_indx, unique_j, dEdD, out_f, M);
}

// Round 3
// 506.473 us; speedup vs baseline: 1.2041x; 1.2041x over previous
//
#include <hip/hip_runtime.h>

#define ND 56
#define HD 64
#define S1 60   // W1T row stride (words): [h=64][d=56 pad 60]
#define S2 68   // W2T row stride (words): [h=64][k=64 pad 68]
#define DEDD_STRIDE 64  // padded dEdD row (floats) -> 256B aligned rows

typedef float v4f __attribute__((ext_vector_type(4)));

__global__ __launch_bounds__(256) void zero_kernel(float* __restrict__ p, int n) {
    int i = blockIdx.x * 256 + threadIdx.x;
    if (i < n) p[i] = 0.f;
}

// Persistent MLP fwd+bwd. One wave = 4 atoms (lane = hidden unit).
// Weights staged once per block in LDS (dual layouts). No __syncthreads
// in the main loop: all per-atom LDS traffic is wave-private.
__global__ __launch_bounds__(256) void mlp_kernel(
    const float* __restrict__ x,        // [natoms*ND]
    const int*   __restrict__ indices,  // [natoms]
    const float* __restrict__ W1,       // [ND*HD]
    const float* __restrict__ b1,       // [HD]
    const float* __restrict__ W2,       // [HD*HD]
    const float* __restrict__ b2,       // [HD]
    const float* __restrict__ W3,       // [HD]
    const float* __restrict__ b3,       // [1]
    float* __restrict__ out_e,          // [nconf]
    float* __restrict__ dEdD,           // [natoms*DEDD_STRIDE]
    int natoms)
{
    __shared__ float W1T[HD * S1 + 4];  // [h][d]  (+4: dx pass reads lane 56..63 slop)
    __shared__ float W2T[HD * S2];      // [h][k]
    __shared__ float b1s[HD], b2s[HD], W3s[HD];
    __shared__ float xs[16 * ND];       // 16 atoms/block-iter
    __shared__ float hbuf[4][4][HD];    // wave, atom, unit  (h1, later g1)
    __shared__ float gbuf[4][4][HD];    // wave, atom, unit  (g2)

    const int tid = threadIdx.x;
    for (int i = tid; i < ND * HD; i += 256) W1T[(i % HD) * S1 + (i / HD)] = W1[i];
    for (int i = tid; i < HD * HD; i += 256) W2T[(i % HD) * S2 + (i / HD)] = W2[i];
    if (tid < HD) { b1s[tid] = b1[tid]; b2s[tid] = b2[tid]; W3s[tid] = W3[tid]; }
    __syncthreads();

    const int w = tid >> 6, lane = tid & 63;
    const float b3v = b3[0];
    const float b1v = b1s[lane], b2v = b2s[lane], w3v = W3s[lane];
    const int nGroups = (natoms + 15) >> 4;

    for (int grp = blockIdx.x; grp < nGroups; grp += gridDim.x) {
        const int abase = grp * 16 + w * 4;   // this wave's 4 atoms

        // stage x rows for this wave's 4 atoms (56 float4s, wave-private)
        if (lane < 56) {
            const int a = lane / 14;
            if (abase + a < natoms)
                reinterpret_cast<float4*>(xs + w * 4 * ND)[lane] =
                    reinterpret_cast<const float4*>(x)[(size_t)abase * 14 + lane];
        }

        float4 acc[4];
        // ---- fwd layer 1: z1[h=lane] per atom ----
        #pragma unroll
        for (int a = 0; a < 4; ++a) acc[a] = float4{0.f, 0.f, 0.f, 0.f};
        #pragma unroll
        for (int i = 0; i < 14; ++i) {
            const float4 wv = *reinterpret_cast<const float4*>(&W1T[lane * S1 + 4 * i]);
            #pragma unroll
            for (int a = 0; a < 4; ++a) {
                const float4 xv = *reinterpret_cast<const float4*>(&xs[(w * 4 + a) * ND + 4 * i]);
                acc[a].x = fmaf(wv.x, xv.x, acc[a].x);
                acc[a].y = fmaf(wv.y, xv.y, acc[a].y);
                acc[a].z = fmaf(wv.z, xv.z, acc[a].z);
                acc[a].w = fmaf(wv.w, xv.w, acc[a].w);
            }
        }
        float z1[4], s1[4];
        #pragma unroll
        for (int a = 0; a < 4; ++a) {
            z1[a] = b1v + ((acc[a].x + acc[a].y) + (acc[a].z + acc[a].w));
            s1[a] = 1.f / (1.f + __expf(-z1[a]));
            hbuf[w][a][lane] = z1[a] * s1[a];
        }

        // ---- fwd layer 2 + energy + g2 ----
        #pragma unroll
        for (int a = 0; a < 4; ++a) acc[a] = float4{0.f, 0.f, 0.f, 0.f};
        #pragma unroll
        for (int i = 0; i < 16; ++i) {
            const float4 wv = *reinterpret_cast<const float4*>(&W2T[lane * S2 + 4 * i]);
            #pragma unroll
            for (int a = 0; a < 4; ++a) {
                const float4 hv = *reinterpret_cast<const float4*>(&hbuf[w][a][4 * i]);
                acc[a].x = fmaf(wv.x, hv.x, acc[a].x);
                acc[a].y = fmaf(wv.y, hv.y, acc[a].y);
                acc[a].z = fmaf(wv.z, hv.z, acc[a].z);
                acc[a].w = fmaf(wv.w, hv.w, acc[a].w);
            }
        }
        float ev[4];
        #pragma unroll
        for (int a = 0; a < 4; ++a) {
            const float z2 = b2v + ((acc[a].x + acc[a].y) + (acc[a].z + acc[a].w));
            const float s2 = 1.f / (1.f + __expf(-z2));
            ev[a] = (z2 * s2) * w3v;
            gbuf[w][a][lane] = w3v * (s2 * (1.f + z2 * (1.f - s2)));
        }
        #pragma unroll
        for (int off = 32; off > 0; off >>= 1) {
            #pragma unroll
            for (int a = 0; a < 4; ++a) ev[a] += __shfl_xor(ev[a], off);
        }
        if (lane == 0) {
            #pragma unroll
            for (int a = 0; a < 4; ++a)
                if (abase + a < natoms) atomicAdd(&out_e[indices[abase + a]], ev[a] + b3v);
        }

        // ---- bwd: dh1 (lane = k), g1 = dh1 * silu'(z1) ----
        #pragma unroll
        for (int a = 0; a < 4; ++a) acc[a] = float4{0.f, 0.f, 0.f, 0.f};
        #pragma unroll
        for (int i = 0; i < 16; ++i) {
            const float w0 = W2T[(4 * i + 0) * S2 + lane];
            const float w1v = W2T[(4 * i + 1) * S2 + lane];
            const float w2v = W2T[(4 * i + 2) * S2 + lane];
            const float w3x = W2T[(4 * i + 3) * S2 + lane];
            #pragma unroll
            for (int a = 0; a < 4; ++a) {
                const float4 gv = *reinterpret_cast<const float4*>(&gbuf[w][a][4 * i]);
                acc[a].x = fmaf(w0, gv.x, acc[a].x);
                acc[a].y = fmaf(w1v, gv.y, acc[a].y);
                acc[a].z = fmaf(w2v, gv.z, acc[a].z);
                acc[a].w = fmaf(w3x, gv.w, acc[a].w);
            }
        }
        #pragma unroll
        for (int a = 0; a < 4; ++a) {
            const float dh1 = (acc[a].x + acc[a].y) + (acc[a].z + acc[a].w);
            hbuf[w][a][lane] = dh1 * (s1[a] * (1.f + z1[a] * (1.f - s1[a])));  // g1 (h1 dead)
        }

        // ---- bwd: dx (lane = d) ----
        #pragma unroll
        for (int a = 0; a < 4; ++a) acc[a] = float4{0.f, 0.f, 0.f, 0.f};
        #pragma unroll
        for (int i = 0; i < 16; ++i) {
            const float w0 = W1T[(4 * i + 0) * S1 + lane];
            const float w1v = W1T[(4 * i + 1) * S1 + lane];
            const float w2v = W1T[(4 * i + 2) * S1 + lane];
            const float w3x = W1T[(4 * i + 3) * S1 + lane];
            #pragma unroll
            for (int a = 0; a < 4; ++a) {
                const float4 gv = *reinterpret_cast<const float4*>(&hbuf[w][a][4 * i]);
                acc[a].x = fmaf(w0, gv.x, acc[a].x);
                acc[a].y = fmaf(w1v, gv.y, acc[a].y);
                acc[a].z = fmaf(w2v, gv.z, acc[a].z);
                acc[a].w = fmaf(w3x, gv.w, acc[a].w);
            }
        }
        if (lane < ND) {
            #pragma unroll
            for (int a = 0; a < 4; ++a)
                if (abase + a < natoms)
                    dEdD[(size_t)(abase + a) * DEDD_STRIDE + lane] =
                        (acc[a].x + acc[a].y) + (acc[a].z + acc[a].w);
        }
    }
}

// 16 lanes per derivative row; nt-loads on the streamed arrays so they
// don't evict the dEdD gather working set from L2.
__global__ __launch_bounds__(256) void force_kernel(
    const float* __restrict__ xd,       // [M*ND]
    const int*   __restrict__ xd_indx,  // [M*3]
    const int*   __restrict__ unique_j, // [M]
    const float* __restrict__ dEdD,     // [natoms*DEDD_STRIDE]
    float* __restrict__ out_f,          // [3*natoms]
    int M)
{
    const long t = (long)blockIdx.x * 256 + threadIdx.x;
    const int  m   = (int)(t >> 4);
    const int  sub = (int)(t & 15);

    float partial = 0.f;
    if (m < M) {
        const int a = __builtin_nontemporal_load(xd_indx + 3 * (size_t)m);
        if (sub < 14) {
            const v4f u = __builtin_nontemporal_load(
                reinterpret_cast<const v4f*>(xd) + (size_t)m * 14 + sub);
            const v4f v = reinterpret_cast<const v4f*>(dEdD + ((size_t)a << 6))[sub];
            partial = fmaf(u.x, v.x, fmaf(u.y, v.y, fmaf(u.z, v.z, u.w * v.w)));
        }
    }
    partial += __shfl_xor(partial, 1);
    partial += __shfl_xor(partial, 2);
    partial += __shfl_xor(partial, 4);
    partial += __shfl_xor(partial, 8);

    if (m < M && sub == 0) {
        const int coord = __builtin_nontemporal_load(xd_indx + 3 * (size_t)m + 2);
        const int j     = __builtin_nontemporal_load(unique_j + m);
        atomicAdd(&out_f[(size_t)j * 3 + coord], partial);
    }
}

extern "C" void kernel_launch(void* const* d_in, const int* in_sizes, int n_in,
                              void* d_out, int out_size, void* d_ws, size_t ws_size,
                              hipStream_t stream) {
    const float* x        = (const float*)d_in[0];
    const float* xd       = (const float*)d_in[1];
    const int*   indices  = (const int*)d_in[2];
    const int*   xd_indx  = (const int*)d_in[4];
    const int*   unique_j = (const int*)d_in[5];
    const float* W1 = (const float*)d_in[6];
    const float* b1 = (const float*)d_in[7];
    const float* W2 = (const float*)d_in[8];
    const float* b2 = (const float*)d_in[9];
    const float* W3 = (const float*)d_in[10];
    const float* b3 = (const float*)d_in[11];

    const int natoms = in_sizes[0] / ND;
    const int M      = in_sizes[1] / ND;
    const int nconf  = in_sizes[3];

    float* out_e = (float*)d_out;          // [nconf]
    float* out_f = out_e + nconf;          // [3*natoms]
    float* dEdD  = (float*)d_ws;           // [natoms*64] floats (12.8 MB)

    // d_out is poisoned once and never re-zeroed between replays: zero it here.
    zero_kernel<<<(out_size + 255) / 256, 256, 0, stream>>>((float*)d_out, out_size);

    const int nGroups = (natoms + 15) >> 4;
    const int mlpGrid = nGroups < 768 ? nGroups : 768;   // 3 blocks/CU (44KB LDS)
    mlp_kernel<<<mlpGrid, 256, 0, stream>>>(
        x, indices, W1, b1, W2, b2, W3, b3, out_e, dEdD, natoms);

    const long fthreads = (long)M * 16;
    force_kernel<<<(unsigned)((fthreads + 255) / 256), 256, 0, stream>>>(
        xd, xd_indx, unique_j, dEdD, out_f, M);
}